// Round 14
// baseline (1862.452 us; speedup 1.0000x reference)
//
#include <hip/hip_runtime.h>
#include <cmath>

// ============================================================================
// DPRNN block (intra BiGRU + inter Skip-GRU), all fp32.
// NUMERICS: inter skip-GRU binary gate round(sigmoid(h@Wp)) -> keep fp32.
// Round 14: dispatch-ID audit showed TWO inter10 dispatches/call (2 t-chunks)
// -> inter GRU = ~1390us = 77% of total; GEMM chain only ~420us. Inter step
// cost (16.7K cy) is barrier-convergence, not issue. v11 cuts 4 barriers/step
// to 3: combineA phase removed; each lane self-serves its rh broadcast values
// from pA (in-register rv01/rv23), summer computes z from pA sums directly.
// z4/rh4 LDS arrays eliminated. All other logic identical to verified v10.
// ============================================================================

typedef float f32x16 __attribute__((ext_vector_type(16)));

__device__ __forceinline__ float sigf(float x) { return 1.0f / (1.0f + expf(-x)); }
__device__ __forceinline__ float rlanef(float v, int l) {
  return __uint_as_float(__builtin_amdgcn_readlane(__float_as_uint(v), (unsigned)l));
}
// LDS-only barrier: orders LDS writes->reads without draining vmem.
__device__ __forceinline__ void ldsbar() {
  asm volatile("s_waitcnt lgkmcnt(0)" ::: "memory");
  __builtin_amdgcn_s_barrier();
  __builtin_amdgcn_sched_barrier(0);
}

// 16-k MAC, 2 column groups
template <int SB>
__device__ __forceinline__ void macP2(const f32x16& u0, const f32x16& u1, float hv,
                                      float& a0, float& a1) {
#pragma unroll
  for (int k = 0; k < 16; ++k) {
    const float hs = rlanef(hv, SB + k);
    a0 = fmaf(u0[k], hs, a0);
    a1 = fmaf(u1[k], hs, a1);
  }
}
// 16-k MAC, 1 column group
template <int SB>
__device__ __forceinline__ void macP1(const f32x16& u, float hv, float& a) {
#pragma unroll
  for (int k = 0; k < 16; ++k) a = fmaf(u[k], rlanef(hv, SB + k), a);
}

// ---------------------------------------------------------------- fill ones
__global__ __launch_bounds__(256) void k_fill_ones(float* __restrict__ p, int n) {
  int i = blockIdx.x * 256 + threadIdx.x;
  if (i < n) p[i] = 1.0f;
}

// ---------------------------------------------------------------- GEMM (xw precompute)
// BM=128, BN=64, BK=16; 256 thr; microtile 8x4.  (r13, verified)
enum { MA_X_FWD = 0, MA_X_BWD = 1, MA_INTER = 2 };

template <int MODE>
__global__ __launch_bounds__(256) void k_gemm_xw(
    const float* __restrict__ A0, const float* __restrict__ A1,
    const float* __restrict__ Bm, const float* __restrict__ bias,
    float* __restrict__ Cm, long M0, int N, int K, int KT)
{
  __shared__ float As[16][132];
  __shared__ float Bs[16][68];
  const int tid = threadIdx.x;
  const int tx = tid & 15, ty = tid >> 4;
  const long row0g = M0 + (long)blockIdx.x * 128;
  const int col0 = blockIdx.y * 64;
  const int lr = tid >> 1;          // A-load row 0..127
  const int lk8 = (tid & 1) * 8;    // A-load k offset 0/8
  const int bk = tid >> 4;          // B-load k 0..15
  const int bc4 = (tid & 15) * 4;   // B-load col group
  float acc[8][4];
#pragma unroll
  for (int i = 0; i < 8; ++i)
#pragma unroll
    for (int j = 0; j < 4; ++j) acc[i][j] = 0.f;

  const long rg = row0g + lr;
  long abase = 0, rowc = 0;
  if (MODE == MA_X_FWD) {
    abase = rg * 128;
  } else if (MODE == MA_X_BWD) {
    const long s = rg >> 6; const int t = (int)(rg & 63);
    abase = (s * 64 + (63 - t)) * 128;
  } else {  // MA_INTER: rg = l*1024 + n
    const int n = (int)(rg & 1023);
    const int l = (int)(rg >> 10);
    rowc = ((long)(n >> 6) * 200 + l) * 64 + (n & 63);
    abase = rowc * 128;
  }

  for (int kt = 0; kt < KT; ++kt) {
    const int k0 = kt * 16;
    {  // ---- A tile: 8 consecutive k for one row ----
      float v[8];
      if (MODE != MA_INTER || kt < 8) {
        const float4 a0 = *reinterpret_cast<const float4*>(&A0[abase + k0 + lk8]);
        const float4 a1 = *reinterpret_cast<const float4*>(&A0[abase + k0 + lk8 + 4]);
        v[0] = a0.x; v[1] = a0.y; v[2] = a0.z; v[3] = a0.w;
        v[4] = a1.x; v[5] = a1.y; v[6] = a1.z; v[7] = a1.w;
      } else {  // inter tail: k 128..143
#pragma unroll
        for (int j = 0; j < 8; ++j) {
          const int k = k0 + lk8 + j;
          v[j] = (k < 128) ? A0[abase + k] : ((k == 128) ? A1[rowc] : 0.f);
        }
      }
#pragma unroll
      for (int j = 0; j < 8; ++j) As[lk8 + j][lr] = v[j];
    }
    {  // ---- B tile ----
      const int k = k0 + bk;
      float4 b4 = make_float4(0.f, 0.f, 0.f, 0.f);
      if (k < K) b4 = *reinterpret_cast<const float4*>(&Bm[(long)k * N + col0 + bc4]);
      *reinterpret_cast<float4*>(&Bs[bk][bc4]) = b4;
    }
    __syncthreads();
#pragma unroll
    for (int kk = 0; kk < 16; ++kk) {
      const float4 a0 = *reinterpret_cast<const float4*>(&As[kk][ty * 8]);
      const float4 a1 = *reinterpret_cast<const float4*>(&As[kk][ty * 8 + 4]);
      const float4 b4 = *reinterpret_cast<const float4*>(&Bs[kk][tx * 4]);
      const float av[8] = {a0.x, a0.y, a0.z, a0.w, a1.x, a1.y, a1.z, a1.w};
      const float bv[4] = {b4.x, b4.y, b4.z, b4.w};
#pragma unroll
      for (int i = 0; i < 8; ++i)
#pragma unroll
        for (int j = 0; j < 4; ++j) acc[i][j] = fmaf(av[i], bv[j], acc[i][j]);
    }
    __syncthreads();
  }
  const float4 bi4 = *reinterpret_cast<const float4*>(&bias[col0 + tx * 4]);
#pragma unroll
  for (int i = 0; i < 8; ++i) {
    const long rl = (long)blockIdx.x * 128 + ty * 8 + i;
    float4 o;
    o.x = acc[i][0] + bi4.x;
    o.y = acc[i][1] + bi4.y;
    o.z = acc[i][2] + bi4.z;
    o.w = acc[i][3] + bi4.w;
    *reinterpret_cast<float4*>(&Cm[rl * (long)N + col0 + tx * 4]) = o;
  }
}

// ---------------------------------------------------------------- intra GRU v5
// VERBATIM from round-11/13 passing source.
__global__ __attribute__((amdgpu_waves_per_eu(4, 4))) __launch_bounds__(256)
void k_gru_intra5(
    const float* __restrict__ xwf, const float* __restrict__ xwb,
    const float* __restrict__ Uf, const float* __restrict__ Ub,
    float* __restrict__ rnn)
{
  const int dir = blockIdx.y;
  const float* __restrict__ xw = dir ? xwb : xwf;
  const float* __restrict__ U  = dir ? Ub : Uf;
  __shared__ float h8[4][64], z8[4][64], rh8[4][64];
  __shared__ float pA[4][4][128];
  __shared__ float pB[4][4][64];
  const int tid = threadIdx.x;
  const int w = tid >> 6, lane = tid & 63;
  const long s0 = (long)blockIdx.x * 4;

  f32x16 uz, ur, uhh;
#pragma unroll
  for (int k = 0; k < 16; ++k) {
    const int row = (w * 16 + k) * 192;
    uz[k]  = U[row + lane];
    ur[k]  = U[row + 64 + lane];
    uhh[k] = U[row + 128 + lane];
  }
  h8[w][lane] = 0.f;
  __syncthreads();

  const long xrow0 = (s0 + w) * 64;
  float xa1 = xw[xrow0 * 192 + lane];
  float xa2 = xw[xrow0 * 192 + 64 + lane];
  float xb  = xw[xrow0 * 192 + 128 + lane];

  for (int t = 0; t < 64; ++t) {
    const int tn = (t < 63) ? t + 1 : t;
    const float xa1n = xw[(xrow0 + tn) * 192 + lane];
    const float xa2n = xw[(xrow0 + tn) * 192 + 64 + lane];
    const float xbn  = xw[(xrow0 + tn) * 192 + 128 + lane];
    {
      const float hv01 = h8[lane >> 5][w * 16 + (lane & 15)];
      const float hv23 = h8[2 + (lane >> 5)][w * 16 + (lane & 15)];
      float az0 = 0.f, ar0 = 0.f, az1 = 0.f, ar1 = 0.f;
      float az2 = 0.f, ar2 = 0.f, az3 = 0.f, ar3 = 0.f;
      macP2<0>(uz, ur, hv01, az0, ar0);
      macP2<32>(uz, ur, hv01, az1, ar1);
      macP2<0>(uz, ur, hv23, az2, ar2);
      macP2<32>(uz, ur, hv23, az3, ar3);
      pA[0][w][lane] = az0; pA[0][w][64 + lane] = ar0;
      pA[1][w][lane] = az1; pA[1][w][64 + lane] = ar1;
      pA[2][w][lane] = az2; pA[2][w][64 + lane] = ar2;
      pA[3][w][lane] = az3; pA[3][w][64 + lane] = ar3;
    }
    ldsbar();
    {
      const float sz = pA[w][0][lane] + pA[w][1][lane] + pA[w][2][lane] +
                       pA[w][3][lane] + xa1;
      const float sr = pA[w][0][64 + lane] + pA[w][1][64 + lane] +
                       pA[w][2][64 + lane] + pA[w][3][64 + lane] + xa2;
      z8[w][lane] = sigf(sz);
      rh8[w][lane] = sigf(sr) * h8[w][lane];
    }
    ldsbar();
    {
      const float rv01 = rh8[lane >> 5][w * 16 + (lane & 15)];
      const float rv23 = rh8[2 + (lane >> 5)][w * 16 + (lane & 15)];
      float a0 = 0.f, a1 = 0.f, a2 = 0.f, a3 = 0.f;
      macP1<0>(uhh, rv01, a0);
      macP1<32>(uhh, rv01, a1);
      macP1<0>(uhh, rv23, a2);
      macP1<32>(uhh, rv23, a3);
      pB[0][w][lane] = a0;
      pB[1][w][lane] = a1;
      pB[2][w][lane] = a2;
      pB[3][w][lane] = a3;
    }
    ldsbar();
    {
      const float pre = pB[w][0][lane] + pB[w][1][lane] + pB[w][2][lane] +
                        pB[w][3][lane] + xb;
      const float hh = tanhf(pre);
      const float z = z8[w][lane];
      const float ho = h8[w][lane];
      const float hn = z * ho + (1.f - z) * hh;
      h8[w][lane] = hn;
      const int tt = dir ? (63 - t) : t;
      rnn[((s0 + w) * 64 + tt) * 128 + dir * 64 + lane] = hn;
    }
    ldsbar();
    xa1 = xa1n; xa2 = xa2n; xb = xbn;
  }
}

// ---------------------------------------------------------------- inter skip-GRU v11
// 256 blocks x 1024 thr (16 waves), 4 seqs, t-chunked. 3 barriers/step:
//  phaseA -> b1 -> rh self-serve (in-register) + phaseB -> b2 -> summer
//  (z from pA sums, hh from pB, blend, gate) -> b3.
// Wave w: kq=w&7 (k-slice kq*16), cg=w>>3. 48 U floats/thread (perfect).
__global__ __attribute__((amdgpu_waves_per_eu(4, 4))) __launch_bounds__(1024)
void k_gru_inter11(
    const float* __restrict__ xw, const float* __restrict__ Ui,
    const float* __restrict__ Wp, const float* __restrict__ bp,
    float* __restrict__ rnn, float* __restrict__ gates,
    float* __restrict__ hstate, float* __restrict__ ustate,
    int t0, int nt)
{
  __shared__ float h4[4][128];
  __shared__ float pA[4][8][256];
  __shared__ float pB[4][8][128];
  __shared__ float uu[4], utt[4];
  const int tid = threadIdx.x;
  const int w = tid >> 6, lane = tid & 63;
  const int kq = w & 7;
  const int kb = kq << 4;         // k-slice base (16 wide)
  const int cg = w >> 3;          // column group (0/1)
  const int n0 = blockIdx.x * 4;
  const int s1 = lane >> 5;       // rh self-serve seq parity (0/1)
  const int cR = kb + (lane & 15);  // rh self-serve column

  f32x16 uz0, uz1, uh;
#pragma unroll
  for (int k = 0; k < 16; ++k) {
    const long r = (long)(kb + k) * 384;
    uz0[k] = Ui[r + cg * 128 + lane];
    uz1[k] = Ui[r + cg * 128 + 64 + lane];
    uh[k]  = Ui[r + 256 + cg * 64 + lane];
  }
  if (tid < 512) {
    const int s = tid >> 7, c = tid & 127;
    h4[s][c] = (t0 == 0) ? 0.f : hstate[(long)(n0 + s) * 128 + c];
  }
  if (tid < 4) {
    utt[tid] = (t0 == 0) ? 1.f : ustate[n0 + tid];
    uu[tid]  = (t0 == 0) ? 1.f : ustate[1024 + n0 + tid];
  }
  const float bp0 = bp[0];
  float wpA = 0.f, wpB = 0.f;
  if (w < 4) { wpA = Wp[lane]; wpB = Wp[64 + lane]; }
  __syncthreads();

  // prefetch xw for dl=0:
  //  all lanes: r-gate pre-activations for (s1, cR) and (s1+2, cR)
  //  waves 0-3: z cols {lane, 64+lane} and hh cols {lane, 64+lane} of seq w
  float xrA = xw[(long)(n0 + s1) * 384 + 128 + cR];
  float xrB = xw[(long)(n0 + 2 + s1) * 384 + 128 + cR];
  float xzA = 0.f, xzB = 0.f, xbA = 0.f, xbB = 0.f;
  if (w < 4) {
    xzA = xw[(long)(n0 + w) * 384 + lane];
    xzB = xw[(long)(n0 + w) * 384 + 64 + lane];
    xbA = xw[(long)(n0 + w) * 384 + 256 + lane];
    xbB = xw[(long)(n0 + w) * 384 + 320 + lane];
  }

  for (int dl = 0; dl < nt; ++dl) {
    const float u0g = uu[0], u1g = uu[1], u2g = uu[2], u3g = uu[3];
    const bool act = (u0g + u1g + u2g + u3g) != 0.f;
    // next-step xw prefetch (off critical path)
    const int dn = (dl + 1 < nt) ? dl + 1 : dl;
    const float xrAn = xw[((long)dn * 1024 + n0 + s1) * 384 + 128 + cR];
    const float xrBn = xw[((long)dn * 1024 + n0 + 2 + s1) * 384 + 128 + cR];
    float xzAn = 0.f, xzBn = 0.f, xbAn = 0.f, xbBn = 0.f;
    if (w < 4) {
      xzAn = xw[((long)dn * 1024 + n0 + w) * 384 + lane];
      xzBn = xw[((long)dn * 1024 + n0 + w) * 384 + 64 + lane];
      xbAn = xw[((long)dn * 1024 + n0 + w) * 384 + 256 + lane];
      xbBn = xw[((long)dn * 1024 + n0 + w) * 384 + 320 + lane];
    }
    if (act) {
      {  // ---- phase A: z/r partial dots (identical to v10) ----
        const float hv01 = h4[lane >> 5][kb + (lane & 15)];
        const float hv23 = h4[2 + (lane >> 5)][kb + (lane & 15)];
        if (u0g != 0.f) {
          float a0 = 0.f, a1 = 0.f;
          macP2<0>(uz0, uz1, hv01, a0, a1);
          pA[0][kq][cg * 128 + lane] = a0;
          pA[0][kq][cg * 128 + 64 + lane] = a1;
        }
        if (u1g != 0.f) {
          float a0 = 0.f, a1 = 0.f;
          macP2<32>(uz0, uz1, hv01, a0, a1);
          pA[1][kq][cg * 128 + lane] = a0;
          pA[1][kq][cg * 128 + 64 + lane] = a1;
        }
        if (u2g != 0.f) {
          float a0 = 0.f, a1 = 0.f;
          macP2<0>(uz0, uz1, hv23, a0, a1);
          pA[2][kq][cg * 128 + lane] = a0;
          pA[2][kq][cg * 128 + 64 + lane] = a1;
        }
        if (u3g != 0.f) {
          float a0 = 0.f, a1 = 0.f;
          macP2<32>(uz0, uz1, hv23, a0, a1);
          pA[3][kq][cg * 128 + lane] = a0;
          pA[3][kq][cg * 128 + 64 + lane] = a1;
        }
      }
      ldsbar();  // b1: pA complete
      // ---- rh self-serve: lane computes exactly the values it broadcasts ----
      // rv01 lanes 0-31: rh[s1][cR]; rv23: rh[s1+2][cR]. (lanes 16-31/48-63
      // duplicate 0-15/32-47 — only lanes 0-15 and 32-47 are broadcast-read.)
      float rv01 = 0.f, rv23 = 0.f;
      {
        const float us1 = s1 ? u1g : u0g;
        const float us3 = s1 ? u3g : u2g;
        if (us1 != 0.f) {
          float sum = xrA;
#pragma unroll
          for (int q = 0; q < 8; ++q) sum += pA[s1][q][128 + cR];
          rv01 = sigf(sum) * h4[s1][cR];
        }
        if (us3 != 0.f) {
          float sum = xrB;
#pragma unroll
          for (int q = 0; q < 8; ++q) sum += pA[2 + s1][q][128 + cR];
          rv23 = sigf(sum) * h4[2 + s1][cR];
        }
      }
      {  // ---- phase B: hh partial dots (rv from registers) ----
        const int cB = cg * 64 + lane;
        if (u0g != 0.f) {
          float b = 0.f;
          macP1<0>(uh, rv01, b);
          pB[0][kq][cB] = b;
        }
        if (u1g != 0.f) {
          float b = 0.f;
          macP1<32>(uh, rv01, b);
          pB[1][kq][cB] = b;
        }
        if (u2g != 0.f) {
          float b = 0.f;
          macP1<0>(uh, rv23, b);
          pB[2][kq][cB] = b;
        }
        if (u3g != 0.f) {
          float b = 0.f;
          macP1<32>(uh, rv23, b);
          pB[3][kq][cB] = b;
        }
      }
      ldsbar();  // b2: pB complete
      if (w < 4) {  // ---- summer + gate, seq = w ----
        const float us = (w == 0) ? u0g : (w == 1) ? u1g : (w == 2) ? u2g : u3g;
        const float hoA = h4[w][lane], hoB = h4[w][64 + lane];
        float hqA, hqB;
        if (us != 0.f) {
          // z self-serve from pA sums
          float sz0 = xzA, sz1 = xzB;
#pragma unroll
          for (int q = 0; q < 8; ++q) {
            sz0 += pA[w][q][lane];
            sz1 += pA[w][q][64 + lane];
          }
          const float zA = sigf(sz0), zB = sigf(sz1);
          float sA = xbA, sB = xbB;
#pragma unroll
          for (int q = 0; q < 8; ++q) {
            sA += pB[w][q][lane];
            sB += pB[w][q][64 + lane];
          }
          const float hhA = tanhf(sA), hhB = tanhf(sB);
          hqA = zA * hoA + (1.f - zA) * hhA;
          hqB = zB * hoB + (1.f - zB) * hhB;
          h4[w][lane] = hqA;
          h4[w][64 + lane] = hqB;
        } else {
          hqA = hoA; hqB = hoB;
        }
        rnn[((long)dl * 1024 + n0 + w) * 128 + lane] = hqA;
        rnn[((long)dl * 1024 + n0 + w) * 128 + 64 + lane] = hqB;
        float p = hqA * wpA + hqB * wpB;
        p += __shfl_xor(p, 32);
        p += __shfl_xor(p, 16);
        p += __shfl_xor(p, 8);
        p += __shfl_xor(p, 4);
        p += __shfl_xor(p, 2);
        p += __shfl_xor(p, 1);
        if (lane == 0) {
          const float delta = sigf(p + bp0);
          const float ut = utt[w];
          gates[(long)(n0 + w) * 200 + t0 + dl] = us;
          const float utn = us * delta + (1.f - us) * (ut + fminf(delta, 1.f - ut));
          utt[w] = utn;
          uu[w] = rintf(utn);  // half-to-even, matches jnp.round
        }
      }
      ldsbar();  // b3: h4/uu ready for next step
    } else {
      // all 4 seqs frozen: h unchanged, still emit rnn snapshot + gates
      if (w < 4) {
        const float hqA = h4[w][lane], hqB = h4[w][64 + lane];
        rnn[((long)dl * 1024 + n0 + w) * 128 + lane] = hqA;
        rnn[((long)dl * 1024 + n0 + w) * 128 + 64 + lane] = hqB;
        float p = hqA * wpA + hqB * wpB;
        p += __shfl_xor(p, 32);
        p += __shfl_xor(p, 16);
        p += __shfl_xor(p, 8);
        p += __shfl_xor(p, 4);
        p += __shfl_xor(p, 2);
        p += __shfl_xor(p, 1);
        if (lane == 0) {
          const float delta = sigf(p + bp0);
          const float ut = utt[w];
          gates[(long)(n0 + w) * 200 + t0 + dl] = 0.f;  // us == 0 here
          const float utn = ut + fminf(delta, 1.f - ut);
          utt[w] = utn;
          uu[w] = rintf(utn);
        }
      }
      ldsbar();
    }
    xrA = xrAn; xrB = xrBn;
    xzA = xzAn; xzB = xzBn; xbA = xbAn; xbB = xbBn;
  }
  if (tid < 512) {
    const int s = tid >> 7, c = tid & 127;
    hstate[(long)(n0 + s) * 128 + c] = h4[s][c];
  }
  if (tid < 4) {
    ustate[n0 + tid] = utt[tid];
    ustate[1024 + n0 + tid] = uu[tid];
  }
}

// ---------------------------------------------------------------- FC + LayerNorm + residual
// BM=64 rows x full 128 cols; 256 thr; microtile 8x4.  (r13, verified)
template <int OM>  // 0 = intra (direct rows), 1 = inter (rows rg = l*1024 + n)
__global__ __launch_bounds__(256) void k_fcln(
    const float* __restrict__ A, const float* __restrict__ Wt,
    const float* __restrict__ bias, const float* __restrict__ gamma,
    const float* __restrict__ beta, const float* __restrict__ resid,
    float* __restrict__ dst, long M0)
{
  __shared__ float As[16][68];    // [k][row 0..63]
  __shared__ float Bs[16][132];   // [k][col 0..127]
  __shared__ float red0[64][33];
  __shared__ float red1[64][33];
  __shared__ float mu_s[64];
  __shared__ float rs_s[64];
  const int tid = threadIdx.x;
  const int tx = tid & 31, ty = tid >> 5;
  const long r0l = (long)blockIdx.x * 64;
  const int lr = tid >> 2;          // A-load row 0..63
  const int lk4 = (tid & 3) * 4;    // A-load k group
  const int bkk = tid >> 4;         // B-load k 0..15
  const int bc8 = (tid & 15) * 8;   // B-load col group
  float acc[8][4];
#pragma unroll
  for (int i = 0; i < 8; ++i)
#pragma unroll
    for (int j = 0; j < 4; ++j) acc[i][j] = 0.f;

  for (int kt = 0; kt < 8; ++kt) {
    const int k0 = kt * 16;
    {
      const float4 a4 = *reinterpret_cast<const float4*>(&A[(r0l + lr) * 128 + k0 + lk4]);
      As[lk4 + 0][lr] = a4.x;
      As[lk4 + 1][lr] = a4.y;
      As[lk4 + 2][lr] = a4.z;
      As[lk4 + 3][lr] = a4.w;
    }
    {
      const float4 w0 = *reinterpret_cast<const float4*>(&Wt[(long)(k0 + bkk) * 128 + bc8]);
      const float4 w1 = *reinterpret_cast<const float4*>(&Wt[(long)(k0 + bkk) * 128 + bc8 + 4]);
      *reinterpret_cast<float4*>(&Bs[bkk][bc8]) = w0;
      *reinterpret_cast<float4*>(&Bs[bkk][bc8 + 4]) = w1;
    }
    __syncthreads();
#pragma unroll
    for (int kk = 0; kk < 16; ++kk) {
      const float4 a0 = *reinterpret_cast<const float4*>(&As[kk][ty * 8]);
      const float4 a1 = *reinterpret_cast<const float4*>(&As[kk][ty * 8 + 4]);
      const float4 b4 = *reinterpret_cast<const float4*>(&Bs[kk][tx * 4]);
      const float av[8] = {a0.x, a0.y, a0.z, a0.w, a1.x, a1.y, a1.z, a1.w};
      const float bv[4] = {b4.x, b4.y, b4.z, b4.w};
#pragma unroll
      for (int i = 0; i < 8; ++i)
#pragma unroll
        for (int j = 0; j < 4; ++j) acc[i][j] = fmaf(av[i], bv[j], acc[i][j]);
    }
    __syncthreads();
  }
  {
    const float4 bb4 = *reinterpret_cast<const float4*>(&bias[tx * 4]);
#pragma unroll
    for (int i = 0; i < 8; ++i) {
      acc[i][0] += bb4.x;
      acc[i][1] += bb4.y;
      acc[i][2] += bb4.z;
      acc[i][3] += bb4.w;
    }
  }
#pragma unroll
  for (int i = 0; i < 8; ++i) {
    const float s = acc[i][0] + acc[i][1] + acc[i][2] + acc[i][3];
    const float q = acc[i][0] * acc[i][0] + acc[i][1] * acc[i][1] +
                    acc[i][2] * acc[i][2] + acc[i][3] * acc[i][3];
    red0[ty * 8 + i][tx] = s;
    red1[ty * 8 + i][tx] = q;
  }
  __syncthreads();
  if (tid < 64) {
    float s = 0.f, q = 0.f;
#pragma unroll
    for (int j = 0; j < 32; ++j) { s += red0[tid][j]; q += red1[tid][j]; }
    const float mu = s * (1.0f / 128.0f);
    const float var = q * (1.0f / 128.0f) - mu * mu;
    mu_s[tid] = mu;
    rs_s[tid] = 1.0f / sqrtf(var + 1e-8f);
  }
  __syncthreads();
  const float4 g4 = *reinterpret_cast<const float4*>(&gamma[tx * 4]);
  const float4 be4 = *reinterpret_cast<const float4*>(&beta[tx * 4]);
#pragma unroll
  for (int i = 0; i < 8; ++i) {
    const int rloc = ty * 8 + i;
    const long rg = M0 + r0l + rloc;
    long off;
    if (OM == 0) {
      off = rg * 128 + tx * 4;
    } else {
      const int n = (int)(rg & 1023);
      const int l = (int)(rg >> 10);
      off = (((long)(n >> 6) * 200 + l) * 64 + (n & 63)) * 128 + tx * 4;
    }
    const float4 r4 = *reinterpret_cast<const float4*>(&resid[off]);
    const float mu = mu_s[rloc], rs = rs_s[rloc];
    float4 o;
    o.x = (acc[i][0] - mu) * rs * g4.x + be4.x + r4.x;
    o.y = (acc[i][1] - mu) * rs * g4.y + be4.y + r4.y;
    o.z = (acc[i][2] - mu) * rs * g4.z + be4.z + r4.z;
    o.w = (acc[i][3] - mu) * rs * g4.w + be4.w + r4.w;
    *reinterpret_cast<float4*>(&dst[off]) = o;
  }
}

// ============================================================================
extern "C" void kernel_launch(void* const* d_in, const int* in_sizes, int n_in,
                              void* d_out, int out_size, void* d_ws, size_t ws_size,
                              hipStream_t stream)
{
  (void)in_sizes; (void)n_in; (void)out_size;
  const float* x    = (const float*)d_in[0];
  const float* scl  = (const float*)d_in[1];
  const float* Wf   = (const float*)d_in[2];
  const float* Uf   = (const float*)d_in[3];
  const float* bf   = (const float*)d_in[4];
  const float* Wb   = (const float*)d_in[5];
  const float* Ub   = (const float*)d_in[6];
  const float* bb   = (const float*)d_in[7];
  const float* Wfc1 = (const float*)d_in[8];
  const float* bfc1 = (const float*)d_in[9];
  const float* gam1 = (const float*)d_in[10];
  const float* bet1 = (const float*)d_in[11];
  const float* Wi   = (const float*)d_in[12];
  const float* Ui   = (const float*)d_in[13];
  const float* bi   = (const float*)d_in[14];
  const float* Wp   = (const float*)d_in[15];
  const float* bp   = (const float*)d_in[16];
  const float* Wfc2 = (const float*)d_in[17];
  const float* bfc2 = (const float*)d_in[18];
  const float* gam2 = (const float*)d_in[19];
  const float* bet2 = (const float*)d_in[20];

  float* outp  = (float*)d_out;
  float* io    = outp;                         // intra_out lives here
  float* onesp = outp + 26214400L;
  float* gates = outp + 26214400L + 12800L;
  float* ws    = (float*)d_ws;
  const long wsf = (long)(ws_size / sizeof(float));

  k_fill_ones<<<50, 256, 0, stream>>>(onesp, 12800);

  // ---------------- intra pass (seq-chunked) ----------------
  long cnI = (wsf / 32768L) & ~7L;
  if (cnI > 3200) cnI = 3200;
  if (cnI < 8) cnI = 8;
  for (long s0 = 0; s0 < 3200; s0 += cnI) {
    const long cn = (3200 - s0 < cnI) ? (3200 - s0) : cnI;
    float* xwf = ws;
    float* xwb = ws + cn * 12288L;
    float* rnn = ws + cn * 24576L;
    const long M = cn * 64;
    dim3 gg((unsigned)(M / 128), 3);
    k_gemm_xw<MA_X_FWD><<<gg, 256, 0, stream>>>(x, nullptr, Wf, bf, xwf, s0 * 64, 192, 128, 8);
    k_gemm_xw<MA_X_BWD><<<gg, 256, 0, stream>>>(x, nullptr, Wb, bb, xwb, s0 * 64, 192, 128, 8);
    dim3 gr((unsigned)(cn / 4), 2);
    k_gru_intra5<<<gr, 256, 0, stream>>>(xwf, xwb, Uf, Ub, rnn);
    k_fcln<0><<<(unsigned)(M / 64), 256, 0, stream>>>(rnn, Wfc1, bfc1, gam1, bet1, x, io, s0 * 64);
  }

  // ---------------- inter pass (t-chunked) ----------------
  const long per_t = 1024L * 384 + 1024L * 128;  // floats per time step
  const long state_f = 1024L * 128 + 3072L;
  long nt_alloc = (wsf - state_f) / per_t;
  if (nt_alloc > 200) nt_alloc = 200;
  if (nt_alloc < 1) nt_alloc = 1;
  float* xwi    = ws;
  float* rnnI   = ws + nt_alloc * 1024L * 384;
  float* hstate = rnnI + nt_alloc * 1024L * 128;
  float* ustate = hstate + 1024L * 128;

  for (long t0 = 0; t0 < 200; t0 += nt_alloc) {
    const int nt = (int)((200 - t0 < nt_alloc) ? (200 - t0) : nt_alloc);
    dim3 gg((unsigned)(8 * nt), 6);
    k_gemm_xw<MA_INTER><<<gg, 256, 0, stream>>>(io, scl, Wi, bi, xwi, t0 * 1024, 384, 129, 9);
    k_gru_inter11<<<256, 1024, 0, stream>>>(xwi, Ui, Wp, bp, rnnI, gates, hstate, ustate,
                                            (int)t0, nt);
    k_fcln<1><<<(unsigned)(16 * nt), 256, 0, stream>>>(rnnI, Wfc2, bfc2, gam2, bet2, io, outp,
                                                       t0 * 1024);
  }
}

// Round 15
// 1759.735 us; speedup vs baseline: 1.0584x; 1.0584x over previous
//
#include <hip/hip_runtime.h>
#include <cmath>

// ============================================================================
// DPRNN block (intra BiGRU + inter Skip-GRU), all fp32.
// NUMERICS: inter skip-GRU binary gate round(sigmoid(h@Wp)) -> keep fp32.
// Round 15: RECOMBINATION of best-measured pieces (no new structures).
// Issue-vs-stall decomposition across v3..v11 shows stall pinned at ~250-300us
// per dispatch (16-wave convergence floor) and total tracking issue count;
// the lowest-issue variant is round-4's wave-specialized inter4 (625us/disp).
// -> inter4 VERBATIM (r4 passing) + r13 GEMM(BM=128,8x4)/fcln(BM=64,8x4)
// + intra5 VERBATIM (r13).
// ============================================================================

typedef float f32x16 __attribute__((ext_vector_type(16)));

__device__ __forceinline__ float sigf(float x) { return 1.0f / (1.0f + expf(-x)); }
__device__ __forceinline__ float rlanef(float v, int l) {
  return __uint_as_float(__builtin_amdgcn_readlane(__float_as_uint(v), (unsigned)l));
}
// LDS-only barrier: orders LDS writes->reads without draining vmem.
__device__ __forceinline__ void ldsbar() {
  asm volatile("s_waitcnt lgkmcnt(0)" ::: "memory");
  __builtin_amdgcn_s_barrier();
  __builtin_amdgcn_sched_barrier(0);
}

// ---- MAC helpers (r4/r13) ----
// 16-k MAC over 4 column groups (inter zr waves)
template <int SB>
__device__ __forceinline__ void mac4(const f32x16& u0, const f32x16& u1,
                                     const f32x16& u2, const f32x16& u3, float hv,
                                     float& a0, float& a1, float& a2, float& a3) {
#pragma unroll
  for (int k = 0; k < 16; ++k) {
    const float hs = rlanef(hv, SB + k);
    a0 = fmaf(u0[k], hs, a0);
    a1 = fmaf(u1[k], hs, a1);
    a2 = fmaf(u2[k], hs, a2);
    a3 = fmaf(u3[k], hs, a3);
  }
}
// 16-k MAC over 2 column groups (inter hh waves / intra zr)
template <int SB>
__device__ __forceinline__ void mac2(const f32x16& u0, const f32x16& u1, float hv,
                                     float& a0, float& a1) {
#pragma unroll
  for (int k = 0; k < 16; ++k) {
    const float hs = rlanef(hv, SB + k);
    a0 = fmaf(u0[k], hs, a0);
    a1 = fmaf(u1[k], hs, a1);
  }
}
// 16-k MAC over 1 column group (intra hh)
template <int SB>
__device__ __forceinline__ void mac1(const f32x16& u, float hv, float& a) {
#pragma unroll
  for (int k = 0; k < 16; ++k) a = fmaf(u[k], rlanef(hv, SB + k), a);
}

// ---------------------------------------------------------------- fill ones
__global__ __launch_bounds__(256) void k_fill_ones(float* __restrict__ p, int n) {
  int i = blockIdx.x * 256 + threadIdx.x;
  if (i < n) p[i] = 1.0f;
}

// ---------------------------------------------------------------- GEMM (xw precompute)
// BM=128, BN=64, BK=16; 256 thr; microtile 8x4.  (r13, verified)
enum { MA_X_FWD = 0, MA_X_BWD = 1, MA_INTER = 2 };

template <int MODE>
__global__ __launch_bounds__(256) void k_gemm_xw(
    const float* __restrict__ A0, const float* __restrict__ A1,
    const float* __restrict__ Bm, const float* __restrict__ bias,
    float* __restrict__ Cm, long M0, int N, int K, int KT)
{
  __shared__ float As[16][132];
  __shared__ float Bs[16][68];
  const int tid = threadIdx.x;
  const int tx = tid & 15, ty = tid >> 4;
  const long row0g = M0 + (long)blockIdx.x * 128;
  const int col0 = blockIdx.y * 64;
  const int lr = tid >> 1;          // A-load row 0..127
  const int lk8 = (tid & 1) * 8;    // A-load k offset 0/8
  const int bk = tid >> 4;          // B-load k 0..15
  const int bc4 = (tid & 15) * 4;   // B-load col group
  float acc[8][4];
#pragma unroll
  for (int i = 0; i < 8; ++i)
#pragma unroll
    for (int j = 0; j < 4; ++j) acc[i][j] = 0.f;

  const long rg = row0g + lr;
  long abase = 0, rowc = 0;
  if (MODE == MA_X_FWD) {
    abase = rg * 128;
  } else if (MODE == MA_X_BWD) {
    const long s = rg >> 6; const int t = (int)(rg & 63);
    abase = (s * 64 + (63 - t)) * 128;
  } else {  // MA_INTER: rg = l*1024 + n
    const int n = (int)(rg & 1023);
    const int l = (int)(rg >> 10);
    rowc = ((long)(n >> 6) * 200 + l) * 64 + (n & 63);
    abase = rowc * 128;
  }

  for (int kt = 0; kt < KT; ++kt) {
    const int k0 = kt * 16;
    {  // ---- A tile: 8 consecutive k for one row ----
      float v[8];
      if (MODE != MA_INTER || kt < 8) {
        const float4 a0 = *reinterpret_cast<const float4*>(&A0[abase + k0 + lk8]);
        const float4 a1 = *reinterpret_cast<const float4*>(&A0[abase + k0 + lk8 + 4]);
        v[0] = a0.x; v[1] = a0.y; v[2] = a0.z; v[3] = a0.w;
        v[4] = a1.x; v[5] = a1.y; v[6] = a1.z; v[7] = a1.w;
      } else {  // inter tail: k 128..143
#pragma unroll
        for (int j = 0; j < 8; ++j) {
          const int k = k0 + lk8 + j;
          v[j] = (k < 128) ? A0[abase + k] : ((k == 128) ? A1[rowc] : 0.f);
        }
      }
#pragma unroll
      for (int j = 0; j < 8; ++j) As[lk8 + j][lr] = v[j];
    }
    {  // ---- B tile ----
      const int k = k0 + bk;
      float4 b4 = make_float4(0.f, 0.f, 0.f, 0.f);
      if (k < K) b4 = *reinterpret_cast<const float4*>(&Bm[(long)k * N + col0 + bc4]);
      *reinterpret_cast<float4*>(&Bs[bk][bc4]) = b4;
    }
    __syncthreads();
#pragma unroll
    for (int kk = 0; kk < 16; ++kk) {
      const float4 a0 = *reinterpret_cast<const float4*>(&As[kk][ty * 8]);
      const float4 a1 = *reinterpret_cast<const float4*>(&As[kk][ty * 8 + 4]);
      const float4 b4 = *reinterpret_cast<const float4*>(&Bs[kk][tx * 4]);
      const float av[8] = {a0.x, a0.y, a0.z, a0.w, a1.x, a1.y, a1.z, a1.w};
      const float bv[4] = {b4.x, b4.y, b4.z, b4.w};
#pragma unroll
      for (int i = 0; i < 8; ++i)
#pragma unroll
        for (int j = 0; j < 4; ++j) acc[i][j] = fmaf(av[i], bv[j], acc[i][j]);
    }
    __syncthreads();
  }
  const float4 bi4 = *reinterpret_cast<const float4*>(&bias[col0 + tx * 4]);
#pragma unroll
  for (int i = 0; i < 8; ++i) {
    const long rl = (long)blockIdx.x * 128 + ty * 8 + i;
    float4 o;
    o.x = acc[i][0] + bi4.x;
    o.y = acc[i][1] + bi4.y;
    o.z = acc[i][2] + bi4.z;
    o.w = acc[i][3] + bi4.w;
    *reinterpret_cast<float4*>(&Cm[rl * (long)N + col0 + tx * 4]) = o;
  }
}

// ---------------------------------------------------------------- intra GRU v5
// VERBATIM from round-13 passing source.
__global__ __attribute__((amdgpu_waves_per_eu(4, 4))) __launch_bounds__(256)
void k_gru_intra5(
    const float* __restrict__ xwf, const float* __restrict__ xwb,
    const float* __restrict__ Uf, const float* __restrict__ Ub,
    float* __restrict__ rnn)
{
  const int dir = blockIdx.y;
  const float* __restrict__ xw = dir ? xwb : xwf;
  const float* __restrict__ U  = dir ? Ub : Uf;
  __shared__ float h8[4][64], z8[4][64], rh8[4][64];
  __shared__ float pA[4][4][128];
  __shared__ float pB[4][4][64];
  const int tid = threadIdx.x;
  const int w = tid >> 6, lane = tid & 63;
  const long s0 = (long)blockIdx.x * 4;

  f32x16 uz, ur, uhh;
#pragma unroll
  for (int k = 0; k < 16; ++k) {
    const int row = (w * 16 + k) * 192;
    uz[k]  = U[row + lane];
    ur[k]  = U[row + 64 + lane];
    uhh[k] = U[row + 128 + lane];
  }
  h8[w][lane] = 0.f;
  __syncthreads();

  const long xrow0 = (s0 + w) * 64;
  float xa1 = xw[xrow0 * 192 + lane];
  float xa2 = xw[xrow0 * 192 + 64 + lane];
  float xb  = xw[xrow0 * 192 + 128 + lane];

  for (int t = 0; t < 64; ++t) {
    const int tn = (t < 63) ? t + 1 : t;
    const float xa1n = xw[(xrow0 + tn) * 192 + lane];
    const float xa2n = xw[(xrow0 + tn) * 192 + 64 + lane];
    const float xbn  = xw[(xrow0 + tn) * 192 + 128 + lane];
    {
      const float hv01 = h8[lane >> 5][w * 16 + (lane & 15)];
      const float hv23 = h8[2 + (lane >> 5)][w * 16 + (lane & 15)];
      float az0 = 0.f, ar0 = 0.f, az1 = 0.f, ar1 = 0.f;
      float az2 = 0.f, ar2 = 0.f, az3 = 0.f, ar3 = 0.f;
      mac2<0>(uz, ur, hv01, az0, ar0);
      mac2<32>(uz, ur, hv01, az1, ar1);
      mac2<0>(uz, ur, hv23, az2, ar2);
      mac2<32>(uz, ur, hv23, az3, ar3);
      pA[0][w][lane] = az0; pA[0][w][64 + lane] = ar0;
      pA[1][w][lane] = az1; pA[1][w][64 + lane] = ar1;
      pA[2][w][lane] = az2; pA[2][w][64 + lane] = ar2;
      pA[3][w][lane] = az3; pA[3][w][64 + lane] = ar3;
    }
    ldsbar();
    {
      const float sz = pA[w][0][lane] + pA[w][1][lane] + pA[w][2][lane] +
                       pA[w][3][lane] + xa1;
      const float sr = pA[w][0][64 + lane] + pA[w][1][64 + lane] +
                       pA[w][2][64 + lane] + pA[w][3][64 + lane] + xa2;
      z8[w][lane] = sigf(sz);
      rh8[w][lane] = sigf(sr) * h8[w][lane];
    }
    ldsbar();
    {
      const float rv01 = rh8[lane >> 5][w * 16 + (lane & 15)];
      const float rv23 = rh8[2 + (lane >> 5)][w * 16 + (lane & 15)];
      float a0 = 0.f, a1 = 0.f, a2 = 0.f, a3 = 0.f;
      mac1<0>(uhh, rv01, a0);
      mac1<32>(uhh, rv01, a1);
      mac1<0>(uhh, rv23, a2);
      mac1<32>(uhh, rv23, a3);
      pB[0][w][lane] = a0;
      pB[1][w][lane] = a1;
      pB[2][w][lane] = a2;
      pB[3][w][lane] = a3;
    }
    ldsbar();
    {
      const float pre = pB[w][0][lane] + pB[w][1][lane] + pB[w][2][lane] +
                        pB[w][3][lane] + xb;
      const float hh = tanhf(pre);
      const float z = z8[w][lane];
      const float ho = h8[w][lane];
      const float hn = z * ho + (1.f - z) * hh;
      h8[w][lane] = hn;
      const int tt = dir ? (63 - t) : t;
      rnn[((s0 + w) * 64 + tt) * 128 + dir * 64 + lane] = hn;
    }
    ldsbar();
    xa1 = xa1n; xa2 = xa2n; xb = xbn;
  }
}

// ---------------------------------------------------------------- inter skip-GRU v4
// VERBATIM from round-4 passing source (best-measured: 621-627us/dispatch).
// 256 blocks x 1024 thr (16 waves), 4 seqs/block, t-chunked [t0, t0+nt).
// zr waves w=0..7: k-slice w*16..+15, cols {j*64+lane} j=0..3, U = 4x f32x16.
// hh waves w=8..15: k-slice (w-8)*16..+15, cols {lane, 64+lane}, U = 2x f32x16.
// u==0 skip: if all 4 seqs inactive, phases A/B skipped (h unchanged).
__global__ __launch_bounds__(1024, 4) void k_gru_inter4(
    const float* __restrict__ xw, const float* __restrict__ Ui,
    const float* __restrict__ Wp, const float* __restrict__ bp,
    float* __restrict__ rnn, float* __restrict__ gates,
    float* __restrict__ hstate, float* __restrict__ ustate,
    int t0, int nt)
{
  __shared__ float h4[4][128], z4[4][128], rh4[4][128];
  __shared__ float pA[4][8][256];
  __shared__ float pB[4][8][128];
  __shared__ float uu[4], utt[4];
  const int tid = threadIdx.x;
  const int w = tid >> 6, lane = tid & 63;
  const int n0 = blockIdx.x * 4;
  const bool isZR = (w < 8);

  f32x16 uA0, uA1, uA2, uA3;
  if (isZR) {
#pragma unroll
    for (int k = 0; k < 16; ++k) {
      const long r = (long)(w * 16 + k) * 384;
      uA0[k] = Ui[r + lane];
      uA1[k] = Ui[r + 64 + lane];
      uA2[k] = Ui[r + 128 + lane];
      uA3[k] = Ui[r + 192 + lane];
    }
  } else {
    const int ks = w - 8;
#pragma unroll
    for (int k = 0; k < 16; ++k) {
      const long r = (long)(ks * 16 + k) * 384 + 256;
      uA0[k] = Ui[r + lane];
      uA1[k] = Ui[r + 64 + lane];
    }
  }
  if (tid < 512) {
    const int s = tid >> 7, c = tid & 127;
    h4[s][c] = (t0 == 0) ? 0.f : hstate[(long)(n0 + s) * 128 + c];
  }
  if (tid < 4) {
    utt[tid] = (t0 == 0) ? 1.f : ustate[n0 + tid];
    uu[tid]  = (t0 == 0) ? 1.f : ustate[1024 + n0 + tid];
  }
  const float bp0 = bp[0];
  float wprA = 0.f, wprB = 0.f;
  if (w < 4) { wprA = Wp[lane]; wprB = Wp[64 + lane]; }
  __syncthreads();

  // prefetch xw for dl=0
  const int cs = w >> 2;               // combiner seq
  const int cc = (w & 3) * 64 + lane;  // combiner zr col (0..255)
  float xc = xw[(long)(n0 + cs) * 384 + cc];
  float xbA = 0.f, xbB = 0.f;
  if (w < 4) {
    xbA = xw[(long)(n0 + w) * 384 + 256 + lane];
    xbB = xw[(long)(n0 + w) * 384 + 320 + lane];
  }

  for (int dl = 0; dl < nt; ++dl) {
    const float u0g = uu[0], u1g = uu[1], u2g = uu[2], u3g = uu[3];
    const bool act = (u0g + u1g + u2g + u3g) != 0.f;
    const int dn = (dl + 1 < nt) ? dl + 1 : dl;
    const float xcn = xw[((long)dn * 1024 + n0 + cs) * 384 + cc];
    float xbAn = 0.f, xbBn = 0.f;
    if (w < 4) {
      xbAn = xw[((long)dn * 1024 + n0 + w) * 384 + 256 + lane];
      xbBn = xw[((long)dn * 1024 + n0 + w) * 384 + 320 + lane];
    }
    if (act) {
      if (isZR) {  // phase A: z/r partial dots, k-slice w*16..+15
        const float hv = h4[lane >> 4][w * 16 + (lane & 15)];
        if (u0g != 0.f) {
          float a0 = 0.f, a1 = 0.f, a2 = 0.f, a3 = 0.f;
          mac4<0>(uA0, uA1, uA2, uA3, hv, a0, a1, a2, a3);
          pA[0][w][lane] = a0; pA[0][w][64 + lane] = a1;
          pA[0][w][128 + lane] = a2; pA[0][w][192 + lane] = a3;
        }
        if (u1g != 0.f) {
          float a0 = 0.f, a1 = 0.f, a2 = 0.f, a3 = 0.f;
          mac4<16>(uA0, uA1, uA2, uA3, hv, a0, a1, a2, a3);
          pA[1][w][lane] = a0; pA[1][w][64 + lane] = a1;
          pA[1][w][128 + lane] = a2; pA[1][w][192 + lane] = a3;
        }
        if (u2g != 0.f) {
          float a0 = 0.f, a1 = 0.f, a2 = 0.f, a3 = 0.f;
          mac4<32>(uA0, uA1, uA2, uA3, hv, a0, a1, a2, a3);
          pA[2][w][lane] = a0; pA[2][w][64 + lane] = a1;
          pA[2][w][128 + lane] = a2; pA[2][w][192 + lane] = a3;
        }
        if (u3g != 0.f) {
          float a0 = 0.f, a1 = 0.f, a2 = 0.f, a3 = 0.f;
          mac4<48>(uA0, uA1, uA2, uA3, hv, a0, a1, a2, a3);
          pA[3][w][lane] = a0; pA[3][w][64 + lane] = a1;
          pA[3][w][128 + lane] = a2; pA[3][w][192 + lane] = a3;
        }
      }
      __syncthreads();  // b1
      {  // combineA
        if (uu[cs] != 0.f) {
          float sum = xc;
#pragma unroll
          for (int ks = 0; ks < 8; ++ks) sum += pA[cs][ks][cc];
          if (cc < 128) z4[cs][cc] = sigf(sum);
          else rh4[cs][cc - 128] = sigf(sum) * h4[cs][cc - 128];
        }
      }
      __syncthreads();  // b2
      if (!isZR) {  // phase B: hh partial dots
        const int ks = w - 8;
        const float rv = rh4[lane >> 4][ks * 16 + (lane & 15)];
        if (u0g != 0.f) {
          float b0 = 0.f, b1 = 0.f;
          mac2<0>(uA0, uA1, rv, b0, b1);
          pB[0][ks][lane] = b0; pB[0][ks][64 + lane] = b1;
        }
        if (u1g != 0.f) {
          float b0 = 0.f, b1 = 0.f;
          mac2<16>(uA0, uA1, rv, b0, b1);
          pB[1][ks][lane] = b0; pB[1][ks][64 + lane] = b1;
        }
        if (u2g != 0.f) {
          float b0 = 0.f, b1 = 0.f;
          mac2<32>(uA0, uA1, rv, b0, b1);
          pB[2][ks][lane] = b0; pB[2][ks][64 + lane] = b1;
        }
        if (u3g != 0.f) {
          float b0 = 0.f, b1 = 0.f;
          mac2<48>(uA0, uA1, rv, b0, b1);
          pB[3][ks][lane] = b0; pB[3][ks][64 + lane] = b1;
        }
      }
      __syncthreads();  // b3
    }
    if (w < 4) {  // summer + gate, seq = w
      const float us = uu[w];
      const float hoA = h4[w][lane], hoB = h4[w][64 + lane];
      float hqA, hqB;
      if (us != 0.f) {
        float sA = xbA, sB = xbB;
#pragma unroll
        for (int ks = 0; ks < 8; ++ks) {
          sA += pB[w][ks][lane];
          sB += pB[w][ks][64 + lane];
        }
        const float hhA = tanhf(sA), hhB = tanhf(sB);
        const float zA = z4[w][lane], zB = z4[w][64 + lane];
        hqA = zA * hoA + (1.f - zA) * hhA;
        hqB = zB * hoB + (1.f - zB) * hhB;
        h4[w][lane] = hqA;
        h4[w][64 + lane] = hqB;
      } else {
        hqA = hoA; hqB = hoB;
      }
      rnn[((long)dl * 1024 + n0 + w) * 128 + lane] = hqA;
      rnn[((long)dl * 1024 + n0 + w) * 128 + 64 + lane] = hqB;
      // gate: 64-lane butterfly
      float p = hqA * wprA + hqB * wprB;
      p += __shfl_xor(p, 32);
      p += __shfl_xor(p, 16);
      p += __shfl_xor(p, 8);
      p += __shfl_xor(p, 4);
      p += __shfl_xor(p, 2);
      p += __shfl_xor(p, 1);
      const float delta = sigf(p + bp0);
      const float ut = utt[w];
      const float utn = us * delta + (1.f - us) * (ut + fminf(delta, 1.f - ut));
      if (lane == 0) {
        gates[(long)(n0 + w) * 200 + t0 + dl] = us;
        utt[w] = utn;
        uu[w] = rintf(utn);  // half-to-even, matches jnp.round
      }
    }
    __syncthreads();  // b4: h4/uu ready for next step
    xc = xcn; xbA = xbAn; xbB = xbBn;
  }
  if (tid < 512) {
    const int s = tid >> 7, c = tid & 127;
    hstate[(long)(n0 + s) * 128 + c] = h4[s][c];
  }
  if (tid < 4) {
    ustate[n0 + tid] = utt[tid];
    ustate[1024 + n0 + tid] = uu[tid];
  }
}

// ---------------------------------------------------------------- FC + LayerNorm + residual
// BM=64 rows x full 128 cols; 256 thr; microtile 8x4.  (r13, verified)
template <int OM>  // 0 = intra (direct rows), 1 = inter (rows rg = l*1024 + n)
__global__ __launch_bounds__(256) void k_fcln(
    const float* __restrict__ A, const float* __restrict__ Wt,
    const float* __restrict__ bias, const float* __restrict__ gamma,
    const float* __restrict__ beta, const float* __restrict__ resid,
    float* __restrict__ dst, long M0)
{
  __shared__ float As[16][68];    // [k][row 0..63]
  __shared__ float Bs[16][132];   // [k][col 0..127]
  __shared__ float red0[64][33];
  __shared__ float red1[64][33];
  __shared__ float mu_s[64];
  __shared__ float rs_s[64];
  const int tid = threadIdx.x;
  const int tx = tid & 31, ty = tid >> 5;
  const long r0l = (long)blockIdx.x * 64;
  const int lr = tid >> 2;          // A-load row 0..63
  const int lk4 = (tid & 3) * 4;    // A-load k group
  const int bkk = tid >> 4;         // B-load k 0..15
  const int bc8 = (tid & 15) * 8;   // B-load col group
  float acc[8][4];
#pragma unroll
  for (int i = 0; i < 8; ++i)
#pragma unroll
    for (int j = 0; j < 4; ++j) acc[i][j] = 0.f;

  for (int kt = 0; kt < 8; ++kt) {
    const int k0 = kt * 16;
    {
      const float4 a4 = *reinterpret_cast<const float4*>(&A[(r0l + lr) * 128 + k0 + lk4]);
      As[lk4 + 0][lr] = a4.x;
      As[lk4 + 1][lr] = a4.y;
      As[lk4 + 2][lr] = a4.z;
      As[lk4 + 3][lr] = a4.w;
    }
    {
      const float4 w0 = *reinterpret_cast<const float4*>(&Wt[(long)(k0 + bkk) * 128 + bc8]);
      const float4 w1 = *reinterpret_cast<const float4*>(&Wt[(long)(k0 + bkk) * 128 + bc8 + 4]);
      *reinterpret_cast<float4*>(&Bs[bkk][bc8]) = w0;
      *reinterpret_cast<float4*>(&Bs[bkk][bc8 + 4]) = w1;
    }
    __syncthreads();
#pragma unroll
    for (int kk = 0; kk < 16; ++kk) {
      const float4 a0 = *reinterpret_cast<const float4*>(&As[kk][ty * 8]);
      const float4 a1 = *reinterpret_cast<const float4*>(&As[kk][ty * 8 + 4]);
      const float4 b4 = *reinterpret_cast<const float4*>(&Bs[kk][tx * 4]);
      const float av[8] = {a0.x, a0.y, a0.z, a0.w, a1.x, a1.y, a1.z, a1.w};
      const float bv[4] = {b4.x, b4.y, b4.z, b4.w};
#pragma unroll
      for (int i = 0; i < 8; ++i)
#pragma unroll
        for (int j = 0; j < 4; ++j) acc[i][j] = fmaf(av[i], bv[j], acc[i][j]);
    }
    __syncthreads();
  }
  {
    const float4 bb4 = *reinterpret_cast<const float4*>(&bias[tx * 4]);
#pragma unroll
    for (int i = 0; i < 8; ++i) {
      acc[i][0] += bb4.x;
      acc[i][1] += bb4.y;
      acc[i][2] += bb4.z;
      acc[i][3] += bb4.w;
    }
  }
#pragma unroll
  for (int i = 0; i < 8; ++i) {
    const float s = acc[i][0] + acc[i][1] + acc[i][2] + acc[i][3];
    const float q = acc[i][0] * acc[i][0] + acc[i][1] * acc[i][1] +
                    acc[i][2] * acc[i][2] + acc[i][3] * acc[i][3];
    red0[ty * 8 + i][tx] = s;
    red1[ty * 8 + i][tx] = q;
  }
  __syncthreads();
  if (tid < 64) {
    float s = 0.f, q = 0.f;
#pragma unroll
    for (int j = 0; j < 32; ++j) { s += red0[tid][j]; q += red1[tid][j]; }
    const float mu = s * (1.0f / 128.0f);
    const float var = q * (1.0f / 128.0f) - mu * mu;
    mu_s[tid] = mu;
    rs_s[tid] = 1.0f / sqrtf(var + 1e-8f);
  }
  __syncthreads();
  const float4 g4 = *reinterpret_cast<const float4*>(&gamma[tx * 4]);
  const float4 be4 = *reinterpret_cast<const float4*>(&beta[tx * 4]);
#pragma unroll
  for (int i = 0; i < 8; ++i) {
    const int rloc = ty * 8 + i;
    const long rg = M0 + r0l + rloc;
    long off;
    if (OM == 0) {
      off = rg * 128 + tx * 4;
    } else {
      const int n = (int)(rg & 1023);
      const int l = (int)(rg >> 10);
      off = (((long)(n >> 6) * 200 + l) * 64 + (n & 63)) * 128 + tx * 4;
    }
    const float4 r4 = *reinterpret_cast<const float4*>(&resid[off]);
    const float mu = mu_s[rloc], rs = rs_s[rloc];
    float4 o;
    o.x = (acc[i][0] - mu) * rs * g4.x + be4.x + r4.x;
    o.y = (acc[i][1] - mu) * rs * g4.y + be4.y + r4.y;
    o.z = (acc[i][2] - mu) * rs * g4.z + be4.z + r4.z;
    o.w = (acc[i][3] - mu) * rs * g4.w + be4.w + r4.w;
    *reinterpret_cast<float4*>(&dst[off]) = o;
  }
}

// ============================================================================
extern "C" void kernel_launch(void* const* d_in, const int* in_sizes, int n_in,
                              void* d_out, int out_size, void* d_ws, size_t ws_size,
                              hipStream_t stream)
{
  (void)in_sizes; (void)n_in; (void)out_size;
  const float* x    = (const float*)d_in[0];
  const float* scl  = (const float*)d_in[1];
  const float* Wf   = (const float*)d_in[2];
  const float* Uf   = (const float*)d_in[3];
  const float* bf   = (const float*)d_in[4];
  const float* Wb   = (const float*)d_in[5];
  const float* Ub   = (const float*)d_in[6];
  const float* bb   = (const float*)d_in[7];
  const float* Wfc1 = (const float*)d_in[8];
  const float* bfc1 = (const float*)d_in[9];
  const float* gam1 = (const float*)d_in[10];
  const float* bet1 = (const float*)d_in[11];
  const float* Wi   = (const float*)d_in[12];
  const float* Ui   = (const float*)d_in[13];
  const float* bi   = (const float*)d_in[14];
  const float* Wp   = (const float*)d_in[15];
  const float* bp   = (const float*)d_in[16];
  const float* Wfc2 = (const float*)d_in[17];
  const float* bfc2 = (const float*)d_in[18];
  const float* gam2 = (const float*)d_in[19];
  const float* bet2 = (const float*)d_in[20];

  float* outp  = (float*)d_out;
  float* io    = outp;                         // intra_out lives here
  float* onesp = outp + 26214400L;
  float* gates = outp + 26214400L + 12800L;
  float* ws    = (float*)d_ws;
  const long wsf = (long)(ws_size / sizeof(float));

  k_fill_ones<<<50, 256, 0, stream>>>(onesp, 12800);

  // ---------------- intra pass (seq-chunked) ----------------
  long cnI = (wsf / 32768L) & ~7L;
  if (cnI > 3200) cnI = 3200;
  if (cnI < 8) cnI = 8;
  for (long s0 = 0; s0 < 3200; s0 += cnI) {
    const long cn = (3200 - s0 < cnI) ? (3200 - s0) : cnI;
    float* xwf = ws;
    float* xwb = ws + cn * 12288L;
    float* rnn = ws + cn * 24576L;
    const long M = cn * 64;
    dim3 gg((unsigned)(M / 128), 3);
    k_gemm_xw<MA_X_FWD><<<gg, 256, 0, stream>>>(x, nullptr, Wf, bf, xwf, s0 * 64, 192, 128, 8);
    k_gemm_xw<MA_X_BWD><<<gg, 256, 0, stream>>>(x, nullptr, Wb, bb, xwb, s0 * 64, 192, 128, 8);
    dim3 gr((unsigned)(cn / 4), 2);
    k_gru_intra5<<<gr, 256, 0, stream>>>(xwf, xwb, Uf, Ub, rnn);
    k_fcln<0><<<(unsigned)(M / 64), 256, 0, stream>>>(rnn, Wfc1, bfc1, gam1, bet1, x, io, s0 * 64);
  }

  // ---------------- inter pass (t-chunked) ----------------
  const long per_t = 1024L * 384 + 1024L * 128;  // floats per time step
  const long state_f = 1024L * 128 + 3072L;
  long nt_alloc = (wsf - state_f) / per_t;
  if (nt_alloc > 200) nt_alloc = 200;
  if (nt_alloc < 1) nt_alloc = 1;
  float* xwi    = ws;
  float* rnnI   = ws + nt_alloc * 1024L * 384;
  float* hstate = rnnI + nt_alloc * 1024L * 128;
  float* ustate = hstate + 1024L * 128;

  for (long t0 = 0; t0 < 200; t0 += nt_alloc) {
    const int nt = (int)((200 - t0 < nt_alloc) ? (200 - t0) : nt_alloc);
    dim3 gg((unsigned)(8 * nt), 6);
    k_gemm_xw<MA_INTER><<<gg, 256, 0, stream>>>(io, scl, Wi, bi, xwi, t0 * 1024, 384, 129, 9);
    k_gru_inter4<<<256, 1024, 0, stream>>>(xwi, Ui, Wp, bp, rnnI, gates, hstate, ustate,
                                           (int)t0, nt);
    k_fcln<1><<<(unsigned)(16 * nt), 256, 0, stream>>>(rnnI, Wfc2, bfc2, gam2, bet2, io, outp,
                                                       t0 * 1024);
  }
}